// Round 13
// baseline (253.950 us; speedup 1.0000x reference)
//
#include <hip/hip_runtime.h>

// ---- problem constants ----
#define L_DIM 197
#define N_DIM 256
#define C_DIM 768
#define CA_DIM 192
#define M_DIM (L_DIM * N_DIM)   // 50432

typedef short s16x8 __attribute__((ext_vector_type(8)));
typedef float f32x4 __attribute__((ext_vector_type(4)));

__device__ __forceinline__ unsigned short f2bf(float f) {
  unsigned x = __builtin_bit_cast(unsigned, f);
  x = (x + 0x7fffu + ((x >> 16) & 1u)) >> 16;   // RNE
  return (unsigned short)x;
}
__device__ __forceinline__ float bflo(unsigned u) { return __builtin_bit_cast(float, u << 16); }
__device__ __forceinline__ float bfhi(unsigned u) { return __builtin_bit_cast(float, u & 0xffff0000u); }

__device__ __forceinline__ void unp8(uint4 v, float* f) {
  f[0] = bflo(v.x); f[1] = bfhi(v.x); f[2] = bflo(v.y); f[3] = bfhi(v.y);
  f[4] = bflo(v.z); f[5] = bfhi(v.z); f[6] = bflo(v.w); f[7] = bfhi(v.w);
}

// packed fp32x2 -> bf16x2 (RNE), single VALU op
__device__ __forceinline__ unsigned cvtpk(float lo, float hi) {
  unsigned r;
  asm("v_cvt_pk_bf16_f32 %0, %1, %2" : "=v"(r) : "v"(lo), "v"(hi));
  return r;
}
// 8 fp32 (two float4) -> s16x8 bf16 fragment
__device__ __forceinline__ s16x8 cvt8(float4 p0, float4 p1) {
  uint4 u;
  u.x = cvtpk(p0.x, p0.y); u.y = cvtpk(p0.z, p0.w);
  u.z = cvtpk(p1.x, p1.y); u.w = cvtpk(p1.z, p1.w);
  return __builtin_bit_cast(s16x8, u);
}

__device__ __forceinline__ void mfma16(f32x4& acc, s16x8 a, s16x8 b) {
  asm("v_mfma_f32_16x16x32_bf16 %0, %1, %2, %0" : "+v"(acc) : "v"(a), "v"(b));
}

// async global->LDS 16B.  HW writes wave-uniform base + lane*16 — every call
// below is arranged so the per-lane LDS byte address == base + 16*lane.
typedef const void __attribute__((address_space(1)))* gp_t;
typedef void __attribute__((address_space(3)))* lp_t;
__device__ __forceinline__ void gl16(const void* g, void* l) {
  __builtin_amdgcn_global_load_lds((gp_t)g, (lp_t)l, 16, 0, 0);
}

// counted vmcnt (T4)
#define WAITVM(n) asm volatile("s_waitcnt vmcnt(" #n ")" ::: "memory")

// bijective XCD-chunk swizzle (m204)
__device__ __forceinline__ int swz(int pid, int nwg) {
  const int q = nwg >> 3, r = nwg & 7, x = pid & 7, s = pid >> 3;
  return (x < r ? x * (q + 1) : r * (q + 1) + (x - r) * q) + s;
}

// ---------------------------------------------------------------------------
// prep: LDS-tiled transpose + fp32->bf16 of all six weight matrices.
// ---------------------------------------------------------------------------
__global__ __launch_bounds__(256) void prep_k(
    const float* __restrict__ fc1_w, const float* __restrict__ mlp_in_w,
    const float* __restrict__ off_fc1_w, const float* __restrict__ fc2_w,
    const float* __restrict__ mlp_out_w, const float* __restrict__ off_fc2_w,
    unsigned short* __restrict__ wa, unsigned short* __restrict__ wc) {
  __shared__ float t[32][33];
  const int b = blockIdx.x;              // 0..863
  const int job = b / 144, tt = b - job * 144;
  const float* in = job == 0 ? fc1_w : job == 1 ? mlp_in_w : job == 2 ? off_fc1_w
                  : job == 3 ? fc2_w : job == 4 ? mlp_out_w : off_fc2_w;
  const int Cc = job < 3 ? 192 : 768;
  const int tc = Cc >> 5;
  const int tr0 = (tt / tc) << 5, tc0 = (tt - (tt / tc) * tc) << 5;
  const int lr = threadIdx.x >> 5, lc = threadIdx.x & 31;
#pragma unroll
  for (int p = 0; p < 4; p++)
    t[p * 8 + lr][lc] = in[(tr0 + p * 8 + lr) * Cc + tc0 + lc];
  __syncthreads();
#pragma unroll
  for (int p = 0; p < 4; p++) {
    const int orow = tc0 + p * 8 + lr;
    const int ocol = tr0 + lc;
    const unsigned short v = f2bf(t[lc][p * 8 + lr]);
    if (job < 3) wa[(job * 192 + orow) * 768 + ocol] = v;
    else         wc[orow * 576 + (job - 3) * 192 + ocol] = v;
  }
}

// ---------------------------------------------------------------------------
// gemm_a: Y = x(50432x768 fp32) @ wa-panel^T.  BM=128, BN=192 (bx = path),
// BK=32, 256 threads = 4 waves (2m x 2n), per-wave 64x96 (24 MFMA/K-step).
// A: fp32 DIRECT from x into registers (8 dwordx4/lane, issued one step
//    early; cvt_pk to bf16 at consume time — compiler vmcnt covers the dep).
// B: gl16 double-buffer (2x12 KB); per-wave WAITVM(8) before the RAW barrier
//    retires own B(kt+1) (oldest 3 of 11) and keeps A(kt+1)'s 8 in flight —
//    the barrier does NOT drain (this was gemm_a's 2x step-time vs gemm_c).
// Fused epilogues (t = fq*4 + r fragment-local):
//   bx0: conv1d over t (2 shuffles)              -> hcat[0:192)
//   bx1: quickGELU(+mlp_in_b)                    -> hcat[192:384)
//   bx2: temporal diff + off_fc1_b (l=0 rows->0) -> hcat[384:576)
// ---------------------------------------------------------------------------
__global__ __launch_bounds__(256, 2) void gemm_a_k(
    const float* __restrict__ x, const unsigned short* __restrict__ wa,
    const float* __restrict__ fc1_b, const float* __restrict__ mlp_in_b,
    const float* __restrict__ cw, const float* __restrict__ cb,
    const float* __restrict__ off_b1, unsigned short* __restrict__ hcat) {
  __shared__ unsigned short Bs[2][192 * 32];   // 2 x 12 KB
  const int tid = threadIdx.x, lane = tid & 63, w = tid >> 6;
  const int lid = swz(blockIdx.x, 3 * 394);
  const int by = lid / 3, bx = lid - by * 3;
  const int m0 = by * 128, n0 = bx * 192;

  const int fr = lane & 15, fq = lane >> 4;
  const int wm = (w >> 1) * 64, wn = (w & 1) * 96;

  // B staging: row sr = tid>>2, chunk sc = (tid&3)*8 -> LDS byte = 16*tid
  const int sr = tid >> 2, sc = (tid & 3) * 8;
  const unsigned short* gB = wa + (size_t)(n0 + sr) * C_DIM + sc;
  auto stageB = [&](int kt, int b) {           // 3 gl16 / thread
    const unsigned short* pb = gB + kt * 32;
    gl16(pb,               &Bs[b][sr * 32 + sc]);
    gl16(pb + 64 * C_DIM,  &Bs[b][(64 + sr) * 32 + sc]);
    gl16(pb + 128 * C_DIM, &Bs[b][(128 + sr) * 32 + sc]);
  };

  // A: per-lane fp32 loads for this wave's 4 fragment rows
  float4 ar[8];
  auto ldA = [&](int kt) {                     // 8 dwordx4 / lane
#pragma unroll
    for (int mi = 0; mi < 4; mi++) {
      const float* p = x + (size_t)(m0 + wm + mi * 16 + fr) * C_DIM + kt * 32 + fq * 8;
      ar[2 * mi]     = *(const float4*)p;
      ar[2 * mi + 1] = *(const float4*)(p + 4);
    }
  };

  f32x4 acc[4][6];
#pragma unroll
  for (int i = 0; i < 4; i++)
#pragma unroll
    for (int j = 0; j < 6; j++) acc[i][j] = (f32x4){0.f, 0.f, 0.f, 0.f};

  // prologue: B(0) staged + waited; A(0) in flight (drained by kt=0 cvt)
  stageB(0, 0);
  ldA(0);
  WAITVM(8);                                   // retire own B(0); keep A(0)
  __builtin_amdgcn_s_barrier();
  asm volatile("" ::: "memory");

  for (int kt = 0; kt < 24; ++kt) {
    const int b = kt & 1;
    // convert A(kt) (compiler inserts the vmcnt for ar deps)
    s16x8 af[4];
#pragma unroll
    for (int mi = 0; mi < 4; mi++) af[mi] = cvt8(ar[2 * mi], ar[2 * mi + 1]);
    // issue next-step loads: B first (older -> retired by WAITVM(8)), A after
    if (kt + 1 < 24) {
      stageB(kt + 1, b ^ 1);
      ldA(kt + 1);
    }
    s16x8 bfv[6];
#pragma unroll
    for (int ni = 0; ni < 6; ni++)
      bfv[ni] = *(const s16x8*)&Bs[b][(wn + ni * 16 + fr) * 32 + fq * 8];
#pragma unroll
    for (int mi = 0; mi < 4; mi++)
#pragma unroll
      for (int ni = 0; ni < 6; ni++) mfma16(acc[mi][ni], af[mi], bfv[ni]);
    if (kt + 1 < 24) {
      WAITVM(8);                               // retire own B(kt+1); keep A(kt+1)
      __builtin_amdgcn_s_barrier();
      asm volatile("" ::: "memory");
    }
  }

  // ---- fused epilogues (t = fq*4 + r within each 16-row fragment) ----
  if (bx == 0) {
#pragma unroll
    for (int ni = 0; ni < 6; ni++) {
      const int ca = wn + ni * 16 + fr;
      const float bv = fc1_b[ca];
      const float w0 = cw[ca * 3], w1 = cw[ca * 3 + 1], w2 = cw[ca * 3 + 2];
      const float cbv = cb[ca];
#pragma unroll
      for (int mi = 0; mi < 4; mi++) {
        const float v0 = acc[mi][ni][0] + bv, v1 = acc[mi][ni][1] + bv;
        const float v2 = acc[mi][ni][2] + bv, v3 = acc[mi][ni][3] + bv;
        const float pv3 = __shfl_up(v3, 16);    // h[t-1] when r==0
        const float nv0 = __shfl_down(v0, 16);  // h[t+1] when r==3
        const float p0 = fq > 0 ? pv3 : 0.f;
        const float n3 = fq < 3 ? nv0 : 0.f;
        const int mb = m0 + wm + mi * 16 + fq * 4;
        hcat[(size_t)(mb + 0) * 576 + ca] = f2bf(w0 * p0 + w1 * v0 + w2 * v1 + cbv);
        hcat[(size_t)(mb + 1) * 576 + ca] = f2bf(w0 * v0 + w1 * v1 + w2 * v2 + cbv);
        hcat[(size_t)(mb + 2) * 576 + ca] = f2bf(w0 * v1 + w1 * v2 + w2 * v3 + cbv);
        hcat[(size_t)(mb + 3) * 576 + ca] = f2bf(w0 * v2 + w1 * v3 + w2 * n3 + cbv);
      }
    }
  } else if (bx == 1) {
#pragma unroll
    for (int ni = 0; ni < 6; ni++) {
      const int ca = wn + ni * 16 + fr;
      const float bv = mlp_in_b[ca];
#pragma unroll
      for (int mi = 0; mi < 4; mi++)
#pragma unroll
        for (int r = 0; r < 4; r++) {
          const int m = m0 + wm + mi * 16 + fq * 4 + r;
          float v = acc[mi][ni][r] + bv;
          v = v / (1.f + __expf(-1.702f * v));   // quick_gelu
          hcat[(size_t)m * 576 + 192 + ca] = f2bf(v);
        }
    }
  } else {
    const bool zrow = (by < 2);                  // rows l==0 (m<256) -> 0
#pragma unroll
    for (int ni = 0; ni < 6; ni++) {
      const int ca = wn + ni * 16 + fr;
      const float bv = off_b1[ca];
#pragma unroll
      for (int mi = 0; mi < 4; mi++) {
        const float v0 = acc[mi][ni][0], v1 = acc[mi][ni][1];
        const float v2 = acc[mi][ni][2], v3 = acc[mi][ni][3];
        const float pv3 = __shfl_up(v3, 16);
        const int mb = m0 + wm + mi * 16 + fq * 4;
        const float o0 = (fq == 0) ? bv : (v0 - pv3 + bv);
        if (zrow) {
          hcat[(size_t)(mb + 0) * 576 + 384 + ca] = 0;
          hcat[(size_t)(mb + 1) * 576 + 384 + ca] = 0;
          hcat[(size_t)(mb + 2) * 576 + 384 + ca] = 0;
          hcat[(size_t)(mb + 3) * 576 + 384 + ca] = 0;
        } else {
          hcat[(size_t)(mb + 0) * 576 + 384 + ca] = f2bf(o0);
          hcat[(size_t)(mb + 1) * 576 + 384 + ca] = f2bf(v1 - v0 + bv);
          hcat[(size_t)(mb + 2) * 576 + 384 + ca] = f2bf(v2 - v1 + bv);
          hcat[(size_t)(mb + 3) * 576 + 384 + ca] = f2bf(v3 - v2 + bv);
        }
      }
    }
  }
}

// ---------------------------------------------------------------------------
// conv3d: spatial-only 3x3 depthwise, IN-PLACE on hcat cols [384,576) rows
// l>=1. One block per (frame n, channel quarter q); temporal diff already done.
// ---------------------------------------------------------------------------
__global__ __launch_bounds__(256) void conv3d_k(
    const float* __restrict__ w3, const float* __restrict__ b2,
    unsigned short* __restrict__ hcat) {
  __shared__ float ds[196 * 48];
  __shared__ float w3s[9 * 48];
  __shared__ float b2s[48];
  const int blk = blockIdx.x;           // 1024 = 256 frames x 4 quarters
  const int n = blk >> 2, q = blk & 3;
  const int ch0 = q * 48;
  const int tid = threadIdx.x;

  for (int j = tid; j < 432; j += 256) {
    const int c = j / 9, tap = j % 9;
    w3s[tap * 48 + c] = w3[(ch0 + c) * 9 + tap];
  }
  if (tid < 48) b2s[tid] = b2[ch0 + tid];

  for (int j = tid; j < 196 * 6; j += 256) {
    const int hw = j / 6, ck = j % 6;
    float dv[8];
    unp8(*(const uint4*)(hcat + ((size_t)(1 + hw) * 256 + n) * 576 + 384 + ch0 + ck * 8), dv);
#pragma unroll
    for (int e = 0; e < 8; e++) ds[hw * 48 + ck * 8 + e] = dv[e];
  }
  __syncthreads();

  for (int j = tid; j < 196 * 6; j += 256) {
    const int hw = j / 6, ck = j % 6;
    const int i = hw / 14, j0 = hw - i * 14;
    float acc[8];
#pragma unroll
    for (int e = 0; e < 8; e++) acc[e] = b2s[ck * 8 + e];
#pragma unroll
    for (int di = 0; di < 3; di++) {
      const int ii = i + di - 1;
      if (ii < 0 || ii >= 14) continue;
#pragma unroll
      for (int dj = 0; dj < 3; dj++) {
        const int jc = j0 + dj - 1;
        if (jc < 0 || jc >= 14) continue;
        const float* dp = &ds[(ii * 14 + jc) * 48 + ck * 8];
        const float* wp = &w3s[(di * 3 + dj) * 48 + ck * 8];
#pragma unroll
        for (int e = 0; e < 8; e++) acc[e] += wp[e] * dp[e];
      }
    }
    unsigned o[4];
#pragma unroll
    for (int e = 0; e < 8; e += 2)
      o[e / 2] = (unsigned)f2bf(acc[e]) | ((unsigned)f2bf(acc[e + 1]) << 16);
    uint4 ov; ov.x = o[0]; ov.y = o[1]; ov.z = o[2]; ov.w = o[3];
    *(uint4*)(hcat + ((size_t)(1 + hw) * 256 + n) * 576 + 384 + ch0 + ck * 8) = ov;
  }
}

// ---------------------------------------------------------------------------
// gemm_c: out = hcat(50432x576) @ wc^T + biases.  BM=128, BN=256, BK=32,
// 256 threads = 4 waves (2m x 2n), per-wave 64x128 -> acc[4][8].
// Triple buffer + counted vmcnt(6) + raw barrier (R10-proven schedule).
// ---------------------------------------------------------------------------
__global__ __launch_bounds__(256, 1) void gemm_c_k(
    const unsigned short* __restrict__ hcat, const unsigned short* __restrict__ wc,
    const float* __restrict__ fc2_b, const float* __restrict__ mlp_out_b,
    const float* __restrict__ off_fc2_b, float* __restrict__ out) {
  __shared__ unsigned short As[3][128 * 32];   // 3 x 8 KB
  __shared__ unsigned short Bs[3][256 * 32];   // 3 x 16 KB
  const int tid = threadIdx.x, lane = tid & 63, w = tid >> 6;
  const int lid = swz(blockIdx.x, 3 * 394);
  const int by = lid / 3, bx = lid - by * 3;
  const int m0 = by * 128, n0 = bx * 256;

  const int sr = tid >> 2, sc = (tid & 3) * 8;      // row 0..63, col chunk
  const unsigned short* gA = hcat + (size_t)(m0 + sr) * 576 + sc;
  const unsigned short* gB = wc + (size_t)(n0 + sr) * 576 + sc;
  auto stage = [&](int kt, int b) {            // 6 gl16 / thread
#pragma unroll
    for (int j = 0; j < 2; j++)
      gl16(gA + kt * 32 + j * 64 * 576, &As[b][(sr + j * 64) * 32 + sc]);
#pragma unroll
    for (int j = 0; j < 4; j++)
      gl16(gB + kt * 32 + j * 64 * 576, &Bs[b][(sr + j * 64) * 32 + sc]);
  };

  f32x4 acc[4][8];
#pragma unroll
  for (int i = 0; i < 4; i++)
#pragma unroll
    for (int j = 0; j < 8; j++) acc[i][j] = (f32x4){0.f, 0.f, 0.f, 0.f};

  const int fr = lane & 15, fq = lane >> 4;
  const int wm = (w >> 1) * 64, wn = (w & 1) * 128;

  stage(0, 0);
#pragma unroll 3
  for (int kt = 0; kt < 18; ++kt) {
    const int b = kt % 3;
    if (kt + 1 < 18) { stage(kt + 1, (kt + 1) % 3); WAITVM(6); }
    else             { WAITVM(0); }
    __builtin_amdgcn_s_barrier();
    asm volatile("" ::: "memory");
    s16x8 af[4], bfv[8];
#pragma unroll
    for (int mi = 0; mi < 4; mi++)
      af[mi] = *(const s16x8*)&As[b][(wm + mi * 16 + fr) * 32 + fq * 8];
#pragma unroll
    for (int ni = 0; ni < 8; ni++)
      bfv[ni] = *(const s16x8*)&Bs[b][(wn + ni * 16 + fr) * 32 + fq * 8];
#pragma unroll
    for (int mi = 0; mi < 4; mi++)
#pragma unroll
      for (int ni = 0; ni < 8; ni++) mfma16(acc[mi][ni], af[mi], bfv[ni]);
  }

  float bv[8];
#pragma unroll
  for (int ni = 0; ni < 8; ni++) {
    const int c = n0 + wn + ni * 16 + fr;
    bv[ni] = fc2_b[c] + mlp_out_b[c] + (by >= 2 ? off_fc2_b[c] : 0.f);
  }
#pragma unroll
  for (int mi = 0; mi < 4; mi++)
#pragma unroll
    for (int r = 0; r < 4; r++) {
      const int m = m0 + wm + mi * 16 + fq * 4 + r;
      float* op = out + (size_t)m * C_DIM + n0 + wn;
#pragma unroll
      for (int ni = 0; ni < 8; ni++) op[ni * 16 + fr] = acc[mi][ni][r] + bv[ni];
    }
}

// ---------------------------------------------------------------------------
extern "C" void kernel_launch(void* const* d_in, const int* in_sizes, int n_in,
                              void* d_out, int out_size, void* d_ws, size_t ws_size,
                              hipStream_t stream) {
  const float* x          = (const float*)d_in[0];
  const float* fc1_w      = (const float*)d_in[2];
  const float* fc1_b      = (const float*)d_in[3];
  const float* conv_w     = (const float*)d_in[4];
  const float* conv_b     = (const float*)d_in[5];
  const float* fc2_w      = (const float*)d_in[6];
  const float* fc2_b      = (const float*)d_in[7];
  const float* off_fc1_w  = (const float*)d_in[8];
  const float* off_fc1_b  = (const float*)d_in[9];
  const float* off_conv_w = (const float*)d_in[10];
  const float* off_conv_b = (const float*)d_in[11];
  const float* off_fc2_w  = (const float*)d_in[12];
  const float* off_fc2_b  = (const float*)d_in[13];
  const float* mlp_in_w   = (const float*)d_in[14];
  const float* mlp_in_b   = (const float*)d_in[15];
  const float* mlp_out_w  = (const float*)d_in[16];
  const float* mlp_out_b  = (const float*)d_in[17];
  float* out = (float*)d_out;

  char* ws = (char*)d_ws;
  unsigned short* hcat = (unsigned short*)(ws);                     // 58.1 MB
  unsigned short* wa   = (unsigned short*)(ws + (size_t)M_DIM * 576 * 2);
  unsigned short* wc   = wa + (size_t)576 * 768;

  prep_k<<<864, 256, 0, stream>>>(fc1_w, mlp_in_w, off_fc1_w, fc2_w, mlp_out_w,
                                  off_fc2_w, wa, wc);
  gemm_a_k<<<1182, 256, 0, stream>>>(x, wa, fc1_b, mlp_in_b, conv_w, conv_b,
                                     off_fc1_b, hcat);
  conv3d_k<<<1024, 256, 0, stream>>>(off_conv_w, off_conv_b, hcat);
  gemm_c_k<<<1182, 256, 0, stream>>>(hcat, wc, fc2_b, mlp_out_b, off_fc2_b, out);
}

// Round 14
// 206.444 us; speedup vs baseline: 1.2301x; 1.2301x over previous
//
#include <hip/hip_runtime.h>

// ---- problem constants ----
#define L_DIM 197
#define N_DIM 256
#define C_DIM 768
#define CA_DIM 192
#define M_DIM (L_DIM * N_DIM)   // 50432

typedef short s16x8 __attribute__((ext_vector_type(8)));
typedef float f32x4 __attribute__((ext_vector_type(4)));

__device__ __forceinline__ unsigned short f2bf(float f) {
  unsigned x = __builtin_bit_cast(unsigned, f);
  x = (x + 0x7fffu + ((x >> 16) & 1u)) >> 16;   // RNE
  return (unsigned short)x;
}
__device__ __forceinline__ float bflo(unsigned u) { return __builtin_bit_cast(float, u << 16); }
__device__ __forceinline__ float bfhi(unsigned u) { return __builtin_bit_cast(float, u & 0xffff0000u); }

__device__ __forceinline__ void unp8(uint4 v, float* f) {
  f[0] = bflo(v.x); f[1] = bfhi(v.x); f[2] = bflo(v.y); f[3] = bfhi(v.y);
  f[4] = bflo(v.z); f[5] = bfhi(v.z); f[6] = bflo(v.w); f[7] = bfhi(v.w);
}

__device__ __forceinline__ void mfma16(f32x4& acc, s16x8 a, s16x8 b) {
  asm("v_mfma_f32_16x16x32_bf16 %0, %1, %2, %0" : "+v"(acc) : "v"(a), "v"(b));
}

// async global->LDS 16B.  HW writes wave-uniform base + lane*16 — every call
// below is arranged so the per-lane LDS byte address == base + 16*lane.
typedef const void __attribute__((address_space(1)))* gp_t;
typedef void __attribute__((address_space(3)))* lp_t;
__device__ __forceinline__ void gl16(const void* g, void* l) {
  __builtin_amdgcn_global_load_lds((gp_t)g, (lp_t)l, 16, 0, 0);
}

// counted vmcnt (T4)
#define WAITVM(n) asm volatile("s_waitcnt vmcnt(" #n ")" ::: "memory")

// bijective XCD-chunk swizzle (m204)
__device__ __forceinline__ int swz(int pid, int nwg) {
  const int q = nwg >> 3, r = nwg & 7, x = pid & 7, s = pid >> 3;
  return (x < r ? x * (q + 1) : r * (q + 1) + (x - r) * q) + s;
}

// ---------------------------------------------------------------------------
// prep_xcvt: one launch, two independent jobs.
//   blocks [0,864):    LDS-tiled transpose + fp32->bf16 of the six weights
//   blocks [864,2912): x fp32 -> bf16 (grid-stride over 2048 blocks)
// ---------------------------------------------------------------------------
__global__ __launch_bounds__(256) void prep_xcvt_k(
    const float* __restrict__ fc1_w, const float* __restrict__ mlp_in_w,
    const float* __restrict__ off_fc1_w, const float* __restrict__ fc2_w,
    const float* __restrict__ mlp_out_w, const float* __restrict__ off_fc2_w,
    const float* __restrict__ x,
    unsigned short* __restrict__ wa, unsigned short* __restrict__ wc,
    unsigned short* __restrict__ xb) {
  __shared__ float t[32][33];
  const int b = blockIdx.x;
  if (b < 864) {
    const int job = b / 144, tt = b - job * 144;
    const float* in = job == 0 ? fc1_w : job == 1 ? mlp_in_w : job == 2 ? off_fc1_w
                    : job == 3 ? fc2_w : job == 4 ? mlp_out_w : off_fc2_w;
    const int Cc = job < 3 ? 192 : 768;
    const int tc = Cc >> 5;
    const int tr0 = (tt / tc) << 5, tc0 = (tt - (tt / tc) * tc) << 5;
    const int lr = threadIdx.x >> 5, lc = threadIdx.x & 31;
#pragma unroll
    for (int p = 0; p < 4; p++)
      t[p * 8 + lr][lc] = in[(tr0 + p * 8 + lr) * Cc + tc0 + lc];
    __syncthreads();
#pragma unroll
    for (int p = 0; p < 4; p++) {
      const int orow = tc0 + p * 8 + lr;
      const int ocol = tr0 + lc;
      const unsigned short v = f2bf(t[lc][p * 8 + lr]);
      if (job < 3) wa[(job * 192 + orow) * 768 + ocol] = v;
      else         wc[orow * 576 + (job - 3) * 192 + ocol] = v;
    }
  } else {
    const int total8 = M_DIM * C_DIM / 8;     // 4,841,472
    const int step = 2048 * 256;
    for (int i = (b - 864) * 256 + threadIdx.x; i < total8; i += step) {
      const float4 a = *(const float4*)(x + (size_t)i * 8);
      const float4 c = *(const float4*)(x + (size_t)i * 8 + 4);
      s16x8 v;
      v[0] = (short)f2bf(a.x); v[1] = (short)f2bf(a.y);
      v[2] = (short)f2bf(a.z); v[3] = (short)f2bf(a.w);
      v[4] = (short)f2bf(c.x); v[5] = (short)f2bf(c.y);
      v[6] = (short)f2bf(c.z); v[7] = (short)f2bf(c.w);
      *(s16x8*)(xb + (size_t)i * 8) = v;
    }
  }
}

// ---------------------------------------------------------------------------
// gemm_a: Y = xb(50432x768 bf16) @ wa-panel^T. BM=128, BN=192 (bx = path),
// BK=32, 256 threads = 4 waves (2m x 2n), per-wave 64x96 (24 MFMA/K-step).
// Both operands via global_load_lds, double-buffered, 2-phase (R8-proven).
// __launch_bounds__(256,3): 96-AGPR acc + 40KB LDS -> target 3 blocks/CU.
// Fused epilogues (t = fq*4 + r fragment-local):
//   bx0: conv1d over t (2 shuffles)              -> hcat[0:192)
//   bx1: quickGELU(+mlp_in_b)                    -> hcat[192:384)
//   bx2: temporal diff + off_fc1_b (l=0 rows->0) -> hcat[384:576)
// ---------------------------------------------------------------------------
__global__ __launch_bounds__(256, 3) void gemm_a_k(
    const unsigned short* __restrict__ xb, const unsigned short* __restrict__ wa,
    const float* __restrict__ fc1_b, const float* __restrict__ mlp_in_b,
    const float* __restrict__ cw, const float* __restrict__ cb,
    const float* __restrict__ off_b1, unsigned short* __restrict__ hcat) {
  __shared__ unsigned short As[2][128 * 32];   // 2 x 8 KB
  __shared__ unsigned short Bs[2][192 * 32];   // 2 x 12 KB
  const int tid = threadIdx.x, lane = tid & 63, w = tid >> 6;
  const int lid = swz(blockIdx.x, 3 * 394);
  const int by = lid / 3, bx = lid - by * 3;
  const int m0 = by * 128, n0 = bx * 192;

  // staging: row sr = tid>>2, col sc = (tid&3)*8  ->  LDS byte = 16*tid
  const int sr = tid >> 2, sc = (tid & 3) * 8;
  const unsigned short* gA0 = xb + (size_t)(m0 + sr) * C_DIM + sc;        // rows 0-63
  const unsigned short* gA1 = xb + (size_t)(m0 + 64 + sr) * C_DIM + sc;   // rows 64-127
  const unsigned short* gB = wa + (size_t)(n0 + sr) * C_DIM + sc;

  auto stage = [&](int kt, int b) {
    gl16(gA0 + kt * 32, &As[b][sr * 32 + sc]);
    gl16(gA1 + kt * 32, &As[b][(64 + sr) * 32 + sc]);
    const unsigned short* pb = gB + kt * 32;
    gl16(pb,               &Bs[b][sr * 32 + sc]);
    gl16(pb + 64 * C_DIM,  &Bs[b][(64 + sr) * 32 + sc]);
    gl16(pb + 128 * C_DIM, &Bs[b][(128 + sr) * 32 + sc]);
  };

  f32x4 acc[4][6];
#pragma unroll
  for (int i = 0; i < 4; i++)
#pragma unroll
    for (int j = 0; j < 6; j++) acc[i][j] = (f32x4){0.f, 0.f, 0.f, 0.f};

  const int fr = lane & 15, fq = lane >> 4;
  const int wm = (w >> 1) * 64, wn = (w & 1) * 96;

  stage(0, 0);
  __syncthreads();
#pragma unroll 2
  for (int kt = 0; kt < 24; ++kt) {
    const int b = kt & 1;
    if (kt + 1 < 24) stage(kt + 1, b ^ 1);
    s16x8 af[4], bfv[6];
#pragma unroll
    for (int mi = 0; mi < 4; mi++)
      af[mi] = *(const s16x8*)&As[b][(wm + mi * 16 + fr) * 32 + fq * 8];
#pragma unroll
    for (int ni = 0; ni < 6; ni++)
      bfv[ni] = *(const s16x8*)&Bs[b][(wn + ni * 16 + fr) * 32 + fq * 8];
#pragma unroll
    for (int mi = 0; mi < 4; mi++)
#pragma unroll
      for (int ni = 0; ni < 6; ni++) mfma16(acc[mi][ni], af[mi], bfv[ni]);
    __syncthreads();
  }

  // ---- fused epilogues (t = fq*4 + r within each 16-row fragment) ----
  if (bx == 0) {
#pragma unroll
    for (int ni = 0; ni < 6; ni++) {
      const int ca = wn + ni * 16 + fr;
      const float bv = fc1_b[ca];
      const float w0 = cw[ca * 3], w1 = cw[ca * 3 + 1], w2 = cw[ca * 3 + 2];
      const float cbv = cb[ca];
#pragma unroll
      for (int mi = 0; mi < 4; mi++) {
        const float v0 = acc[mi][ni][0] + bv, v1 = acc[mi][ni][1] + bv;
        const float v2 = acc[mi][ni][2] + bv, v3 = acc[mi][ni][3] + bv;
        const float pv3 = __shfl_up(v3, 16);    // h[t-1] when r==0
        const float nv0 = __shfl_down(v0, 16);  // h[t+1] when r==3
        const float p0 = fq > 0 ? pv3 : 0.f;
        const float n3 = fq < 3 ? nv0 : 0.f;
        const int mb = m0 + wm + mi * 16 + fq * 4;
        hcat[(size_t)(mb + 0) * 576 + ca] = f2bf(w0 * p0 + w1 * v0 + w2 * v1 + cbv);
        hcat[(size_t)(mb + 1) * 576 + ca] = f2bf(w0 * v0 + w1 * v1 + w2 * v2 + cbv);
        hcat[(size_t)(mb + 2) * 576 + ca] = f2bf(w0 * v1 + w1 * v2 + w2 * v3 + cbv);
        hcat[(size_t)(mb + 3) * 576 + ca] = f2bf(w0 * v2 + w1 * v3 + w2 * n3 + cbv);
      }
    }
  } else if (bx == 1) {
#pragma unroll
    for (int ni = 0; ni < 6; ni++) {
      const int ca = wn + ni * 16 + fr;
      const float bv = mlp_in_b[ca];
#pragma unroll
      for (int mi = 0; mi < 4; mi++)
#pragma unroll
        for (int r = 0; r < 4; r++) {
          const int m = m0 + wm + mi * 16 + fq * 4 + r;
          float v = acc[mi][ni][r] + bv;
          v = v / (1.f + __expf(-1.702f * v));   // quick_gelu
          hcat[(size_t)m * 576 + 192 + ca] = f2bf(v);
        }
    }
  } else {
    const bool zrow = (by < 2);                  // rows l==0 (m<256) -> 0
#pragma unroll
    for (int ni = 0; ni < 6; ni++) {
      const int ca = wn + ni * 16 + fr;
      const float bv = off_b1[ca];
#pragma unroll
      for (int mi = 0; mi < 4; mi++) {
        const float v0 = acc[mi][ni][0], v1 = acc[mi][ni][1];
        const float v2 = acc[mi][ni][2], v3 = acc[mi][ni][3];
        const float pv3 = __shfl_up(v3, 16);
        const int mb = m0 + wm + mi * 16 + fq * 4;
        const float o0 = (fq == 0) ? bv : (v0 - pv3 + bv);
        if (zrow) {
          hcat[(size_t)(mb + 0) * 576 + 384 + ca] = 0;
          hcat[(size_t)(mb + 1) * 576 + 384 + ca] = 0;
          hcat[(size_t)(mb + 2) * 576 + 384 + ca] = 0;
          hcat[(size_t)(mb + 3) * 576 + 384 + ca] = 0;
        } else {
          hcat[(size_t)(mb + 0) * 576 + 384 + ca] = f2bf(o0);
          hcat[(size_t)(mb + 1) * 576 + 384 + ca] = f2bf(v1 - v0 + bv);
          hcat[(size_t)(mb + 2) * 576 + 384 + ca] = f2bf(v2 - v1 + bv);
          hcat[(size_t)(mb + 3) * 576 + 384 + ca] = f2bf(v3 - v2 + bv);
        }
      }
    }
  }
}

// ---------------------------------------------------------------------------
// conv3d: spatial-only 3x3 depthwise, IN-PLACE on hcat cols [384,576) rows
// l>=1. One block per (frame n, channel quarter q); temporal diff already done.
// ---------------------------------------------------------------------------
__global__ __launch_bounds__(256) void conv3d_k(
    const float* __restrict__ w3, const float* __restrict__ b2,
    unsigned short* __restrict__ hcat) {
  __shared__ float ds[196 * 48];
  __shared__ float w3s[9 * 48];
  __shared__ float b2s[48];
  const int blk = blockIdx.x;           // 1024 = 256 frames x 4 quarters
  const int n = blk >> 2, q = blk & 3;
  const int ch0 = q * 48;
  const int tid = threadIdx.x;

  for (int j = tid; j < 432; j += 256) {
    const int c = j / 9, tap = j % 9;
    w3s[tap * 48 + c] = w3[(ch0 + c) * 9 + tap];
  }
  if (tid < 48) b2s[tid] = b2[ch0 + tid];

  for (int j = tid; j < 196 * 6; j += 256) {
    const int hw = j / 6, ck = j % 6;
    float dv[8];
    unp8(*(const uint4*)(hcat + ((size_t)(1 + hw) * 256 + n) * 576 + 384 + ch0 + ck * 8), dv);
#pragma unroll
    for (int e = 0; e < 8; e++) ds[hw * 48 + ck * 8 + e] = dv[e];
  }
  __syncthreads();

  for (int j = tid; j < 196 * 6; j += 256) {
    const int hw = j / 6, ck = j % 6;
    const int i = hw / 14, j0 = hw - i * 14;
    float acc[8];
#pragma unroll
    for (int e = 0; e < 8; e++) acc[e] = b2s[ck * 8 + e];
#pragma unroll
    for (int di = 0; di < 3; di++) {
      const int ii = i + di - 1;
      if (ii < 0 || ii >= 14) continue;
#pragma unroll
      for (int dj = 0; dj < 3; dj++) {
        const int jc = j0 + dj - 1;
        if (jc < 0 || jc >= 14) continue;
        const float* dp = &ds[(ii * 14 + jc) * 48 + ck * 8];
        const float* wp = &w3s[(di * 3 + dj) * 48 + ck * 8];
#pragma unroll
        for (int e = 0; e < 8; e++) acc[e] += wp[e] * dp[e];
      }
    }
    unsigned o[4];
#pragma unroll
    for (int e = 0; e < 8; e += 2)
      o[e / 2] = (unsigned)f2bf(acc[e]) | ((unsigned)f2bf(acc[e + 1]) << 16);
    uint4 ov; ov.x = o[0]; ov.y = o[1]; ov.z = o[2]; ov.w = o[3];
    *(uint4*)(hcat + ((size_t)(1 + hw) * 256 + n) * 576 + 384 + ch0 + ck * 8) = ov;
  }
}

// ---------------------------------------------------------------------------
// gemm_c: out = hcat(50432x576) @ wc^T + biases.  BM=128, BN=256, BK=32,
// 256 threads = 4 waves (2m x 2n), per-wave 64x128 -> acc[4][8].
// Triple buffer + counted vmcnt(6) + raw barrier (R10-proven, ~57 us).
// ---------------------------------------------------------------------------
__global__ __launch_bounds__(256, 1) void gemm_c_k(
    const unsigned short* __restrict__ hcat, const unsigned short* __restrict__ wc,
    const float* __restrict__ fc2_b, const float* __restrict__ mlp_out_b,
    const float* __restrict__ off_fc2_b, float* __restrict__ out) {
  __shared__ unsigned short As[3][128 * 32];   // 3 x 8 KB
  __shared__ unsigned short Bs[3][256 * 32];   // 3 x 16 KB
  const int tid = threadIdx.x, lane = tid & 63, w = tid >> 6;
  const int lid = swz(blockIdx.x, 3 * 394);
  const int by = lid / 3, bx = lid - by * 3;
  const int m0 = by * 128, n0 = bx * 256;

  const int sr = tid >> 2, sc = (tid & 3) * 8;      // row 0..63, col chunk
  const unsigned short* gA = hcat + (size_t)(m0 + sr) * 576 + sc;
  const unsigned short* gB = wc + (size_t)(n0 + sr) * 576 + sc;
  auto stage = [&](int kt, int b) {            // 6 gl16 / thread
#pragma unroll
    for (int j = 0; j < 2; j++)
      gl16(gA + kt * 32 + j * 64 * 576, &As[b][(sr + j * 64) * 32 + sc]);
#pragma unroll
    for (int j = 0; j < 4; j++)
      gl16(gB + kt * 32 + j * 64 * 576, &Bs[b][(sr + j * 64) * 32 + sc]);
  };

  f32x4 acc[4][8];
#pragma unroll
  for (int i = 0; i < 4; i++)
#pragma unroll
    for (int j = 0; j < 8; j++) acc[i][j] = (f32x4){0.f, 0.f, 0.f, 0.f};

  const int fr = lane & 15, fq = lane >> 4;
  const int wm = (w >> 1) * 64, wn = (w & 1) * 128;

  stage(0, 0);
#pragma unroll 3
  for (int kt = 0; kt < 18; ++kt) {
    const int b = kt % 3;
    if (kt + 1 < 18) { stage(kt + 1, (kt + 1) % 3); WAITVM(6); }
    else             { WAITVM(0); }
    __builtin_amdgcn_s_barrier();
    asm volatile("" ::: "memory");
    s16x8 af[4], bfv[8];
#pragma unroll
    for (int mi = 0; mi < 4; mi++)
      af[mi] = *(const s16x8*)&As[b][(wm + mi * 16 + fr) * 32 + fq * 8];
#pragma unroll
    for (int ni = 0; ni < 8; ni++)
      bfv[ni] = *(const s16x8*)&Bs[b][(wn + ni * 16 + fr) * 32 + fq * 8];
#pragma unroll
    for (int mi = 0; mi < 4; mi++)
#pragma unroll
      for (int ni = 0; ni < 8; ni++) mfma16(acc[mi][ni], af[mi], bfv[ni]);
  }

  float bv[8];
#pragma unroll
  for (int ni = 0; ni < 8; ni++) {
    const int c = n0 + wn + ni * 16 + fr;
    bv[ni] = fc2_b[c] + mlp_out_b[c] + (by >= 2 ? off_fc2_b[c] : 0.f);
  }
#pragma unroll
  for (int mi = 0; mi < 4; mi++)
#pragma unroll
    for (int r = 0; r < 4; r++) {
      const int m = m0 + wm + mi * 16 + fq * 4 + r;
      float* op = out + (size_t)m * C_DIM + n0 + wn;
#pragma unroll
      for (int ni = 0; ni < 8; ni++) op[ni * 16 + fr] = acc[mi][ni][r] + bv[ni];
    }
}

// ---------------------------------------------------------------------------
extern "C" void kernel_launch(void* const* d_in, const int* in_sizes, int n_in,
                              void* d_out, int out_size, void* d_ws, size_t ws_size,
                              hipStream_t stream) {
  const float* x          = (const float*)d_in[0];
  const float* fc1_w      = (const float*)d_in[2];
  const float* fc1_b      = (const float*)d_in[3];
  const float* conv_w     = (const float*)d_in[4];
  const float* conv_b     = (const float*)d_in[5];
  const float* fc2_w      = (const float*)d_in[6];
  const float* fc2_b      = (const float*)d_in[7];
  const float* off_fc1_w  = (const float*)d_in[8];
  const float* off_fc1_b  = (const float*)d_in[9];
  const float* off_conv_w = (const float*)d_in[10];
  const float* off_conv_b = (const float*)d_in[11];
  const float* off_fc2_w  = (const float*)d_in[12];
  const float* off_fc2_b  = (const float*)d_in[13];
  const float* mlp_in_w   = (const float*)d_in[14];
  const float* mlp_in_b   = (const float*)d_in[15];
  const float* mlp_out_w  = (const float*)d_in[16];
  const float* mlp_out_b  = (const float*)d_in[17];
  float* out = (float*)d_out;

  char* ws = (char*)d_ws;
  unsigned short* xb   = (unsigned short*)(ws);                       // 77.5 MB
  unsigned short* hcat = (unsigned short*)(ws + (size_t)M_DIM * C_DIM * 2);  // 58.1 MB
  unsigned short* wa   = (unsigned short*)(ws + (size_t)M_DIM * C_DIM * 2
                                              + (size_t)M_DIM * 576 * 2);
  unsigned short* wc   = wa + (size_t)576 * 768;

  prep_xcvt_k<<<2912, 256, 0, stream>>>(fc1_w, mlp_in_w, off_fc1_w, fc2_w,
                                        mlp_out_w, off_fc2_w, x, wa, wc, xb);
  gemm_a_k<<<1182, 256, 0, stream>>>(xb, wa, fc1_b, mlp_in_b, conv_w, conv_b,
                                     off_fc1_b, hcat);
  conv3d_k<<<1024, 256, 0, stream>>>(off_conv_w, off_conv_b, hcat);
  gemm_c_k<<<1182, 256, 0, stream>>>(hcat, wc, fc2_b, mlp_out_b, off_fc2_b, out);
}